// Round 2
// baseline (9619.250 us; speedup 1.0000x reference)
//
#include <hip/hip_runtime.h>
#include <math.h>

// SRHDR fused windowed-attention block, MI355X round 2 (correctness-first, f32 VALU).
// K1 (k_win): per-window [576 wgs]: gather+LN1 -> SA (4x 32-chunk scores+PV) ->
//   +POS -> EA1/EA2 -> GEGLU-MLP1 streamed accumulation -> fc2 -> unwindow+residual -> d_out (x1)
// K2 (k_mlp2): per-64-pixel tile in-place on d_out: LN2 -> GEGLU-MLP2 -> residual.

typedef unsigned short u16;
typedef unsigned int u32;

#define DEVINL __device__ __forceinline__

DEVINL float blo(u32 u){ return __uint_as_float(u << 16); }
DEVINL float bhi(u32 u){ return __uint_as_float(u & 0xffff0000u); }
DEVINL float b2f(u16 h){ return __uint_as_float(((u32)h) << 16); }
DEVINL u16 f2b(float f){
  u32 u = __float_as_uint(f);
  return (u16)((u + 0x7fffu + ((u >> 16) & 1u)) >> 16);   // RNE
}
DEVINL float gelu_ex(float x){ return 0.5f * x * (1.0f + erff(x * 0.7071067811865476f)); }

#define UNP8(q, B, u) \
  q[(B)+0]=blo(u.x); q[(B)+1]=bhi(u.x); q[(B)+2]=blo(u.y); q[(B)+3]=bhi(u.y); \
  q[(B)+4]=blo(u.z); q[(B)+5]=bhi(u.z); q[(B)+6]=blo(u.w); q[(B)+7]=bhi(u.w);

#define DOT8(a, u, q, B) \
  a = fmaf(q[(B)+0], blo(u.x), a); a = fmaf(q[(B)+1], bhi(u.x), a); \
  a = fmaf(q[(B)+2], blo(u.y), a); a = fmaf(q[(B)+3], bhi(u.y), a); \
  a = fmaf(q[(B)+4], blo(u.z), a); a = fmaf(q[(B)+5], bhi(u.z), a); \
  a = fmaf(q[(B)+6], blo(u.w), a); a = fmaf(q[(B)+7], bhi(u.w), a);

#define AXPY8(o, B, pm, u) \
  o[(B)+0] = fmaf(pm, blo(u.x), o[(B)+0]); o[(B)+1] = fmaf(pm, bhi(u.x), o[(B)+1]); \
  o[(B)+2] = fmaf(pm, blo(u.y), o[(B)+2]); o[(B)+3] = fmaf(pm, bhi(u.y), o[(B)+3]); \
  o[(B)+4] = fmaf(pm, blo(u.z), o[(B)+4]); o[(B)+5] = fmaf(pm, bhi(u.z), o[(B)+5]); \
  o[(B)+6] = fmaf(pm, blo(u.w), o[(B)+6]); o[(B)+7] = fmaf(pm, bhi(u.w), o[(B)+7]);

// NOTE: param named W (capital) — member access .w must not collide with a macro param.
#define FMA4A(acc, B, a, W) \
  acc[(B)+0] = fmaf(a, W.x, acc[(B)+0]); acc[(B)+1] = fmaf(a, W.y, acc[(B)+1]); \
  acc[(B)+2] = fmaf(a, W.z, acc[(B)+2]); acc[(B)+3] = fmaf(a, W.w, acc[(B)+3]);

// projection: dst[h][n][c] = sum_k XW[e][n][k] * Wg[k][colbase + h*32 + c] * scale  (bf16 store)
// thread map: h = t>>6 (wave), c = t&31, nh2 = (t>>5)&1 -> 32 n's per thread, weight col in regs.
DEVINL void proj(u16* __restrict__ dst, const float* __restrict__ XW, int e,
                 const float* __restrict__ Wg, int colbase, float scale, int t)
{
  const int h = t >> 6, c = t & 31, nh2 = (t >> 5) & 1;
  const int col = colbase + (h << 5) + c;
  float wr[32];
  #pragma unroll
  for (int k = 0; k < 32; ++k) wr[k] = Wg[k * 384 + col] * scale;
  const float* src = XW + (e << 11);
  u16* d = dst + (h << 11) + c;
  const int n0 = nh2 << 5;
  for (int ni = 0; ni < 32; ++ni){
    const int n = n0 + ni;
    const float4* row = (const float4*)(src + (n << 5));
    float acc = 0.f;
    #pragma unroll
    for (int q = 0; q < 8; ++q){
      float4 r = row[q];
      acc = fmaf(r.x, wr[4*q+0], acc);
      acc = fmaf(r.y, wr[4*q+1], acc);
      acc = fmaf(r.z, wr[4*q+2], acc);
      acc = fmaf(r.w, wr[4*q+3], acc);
    }
    d[n << 5] = f2b(acc);
  }
}

// scores: wave h, lane n:  sc[m] (+)= sum_c q[h][n][c] * k[h][m][c]
template<bool ACC>
DEVINL void score64(const u16* __restrict__ qb, const u16* __restrict__ kb,
                    float* sc, int t)
{
  const int h = t >> 6, n = t & 63;
  float q[32];
  {
    const uint4* qr = (const uint4*)(qb + (h << 11) + (n << 5));
    uint4 u0 = qr[0], u1 = qr[1], u2 = qr[2], u3 = qr[3];
    UNP8(q, 0, u0); UNP8(q, 8, u1); UNP8(q, 16, u2); UNP8(q, 24, u3);
  }
  const u16* kbase = kb + (h << 11);
  #pragma unroll
  for (int m = 0; m < 64; ++m){
    const uint4* kr = (const uint4*)(kbase + (m << 5));
    uint4 u0 = kr[0], u1 = kr[1], u2 = kr[2], u3 = kr[3];
    float a = 0.f;
    DOT8(a, u0, q, 0); DOT8(a, u1, q, 8); DOT8(a, u2, q, 16); DOT8(a, u3, q, 24);
    if (ACC) sc[m] += a; else sc[m] = a;
  }
}

DEVINL float softmax64(float* sc){
  float mx = sc[0];
  #pragma unroll
  for (int m = 1; m < 64; ++m) mx = fmaxf(mx, sc[m]);
  float sum = 0.f;
  #pragma unroll
  for (int m = 0; m < 64; ++m){ const float p = __expf(sc[m] - mx); sc[m] = p; sum += p; }
  return 1.f / sum;
}

// PV: out[h][n][c] = rinv * sum_m p[m] * v[h][m][c]; store TRANSPOSED oc[h][c][n] (bank-friendly for mlp_acc)
DEVINL void pv_store(const u16* __restrict__ vb, const float* p, float rinv,
                     u16* __restrict__ oc, int t)
{
  const int h = t >> 6, n = t & 63;
  float o[32];
  #pragma unroll
  for (int i = 0; i < 32; ++i) o[i] = 0.f;
  const u16* vbase = vb + (h << 11);
  #pragma unroll
  for (int m = 0; m < 64; ++m){
    const uint4* vr = (const uint4*)(vbase + (m << 5));
    uint4 u0 = vr[0], u1 = vr[1], u2 = vr[2], u3 = vr[3];
    const float pm = p[m];
    AXPY8(o, 0, pm, u0); AXPY8(o, 8, pm, u1); AXPY8(o, 16, pm, u2); AXPY8(o, 24, pm, u3);
  }
  u16* ob = oc + (h << 11) + n;
  #pragma unroll
  for (int c = 0; c < 32; ++c) ob[c << 6] = f2b(o[c] * rinv);
}

// streamed MLP1 accumulation: acc[n][j] += oc[h4][k][n] * W[rowbase + h4*128 + k][j]
// thread map: n = t>>2, jb = t&3 (j = jb*32..+31)
DEVINL void mlp_acc(const u16* __restrict__ oc, int rowbase,
                    const float* __restrict__ W1, const float* __restrict__ W2g,
                    float* a1, float* a2, int t)
{
  const int n = t >> 2, jb = t & 3;
  const int joff = jb << 5;
  for (int h4 = 0; h4 < 4; ++h4){
    const u16* op = oc + (h4 << 11) + n;
    const float* w1b = W1  + (rowbase + (h4 << 7)) * 128 + joff;
    const float* w2b = W2g + (rowbase + (h4 << 7)) * 128 + joff;
    for (int k = 0; k < 32; ++k){
      const float a = b2f(op[k << 6]);
      const float4* w1 = (const float4*)(w1b + k * 128);
      const float4* w2 = (const float4*)(w2b + k * 128);
      #pragma unroll
      for (int q = 0; q < 8; ++q){ float4 wa = w1[q]; FMA4A(a1, 4*q, a, wa); }
      #pragma unroll
      for (int q = 0; q < 8; ++q){ float4 wb = w2[q]; FMA4A(a2, 4*q, a, wb); }
    }
  }
}

__global__ __launch_bounds__(256, 2)
void k_win(const float* __restrict__ X,
           const float* __restrict__ Wea, const float* __restrict__ Wsa,
           const float* __restrict__ g1, const float* __restrict__ b1,
           const float* __restrict__ rpb,
           const float* __restrict__ W11, const float* __restrict__ B11,
           const float* __restrict__ W12, const float* __restrict__ B12,
           const float* __restrict__ W2,  const float* __restrict__ B2v,
           float* __restrict__ OUT)
{
  __shared__ __align__(16) float XW[4 * 64 * 32];     // 32KB  LN'd window, [e][n][cc]
  __shared__ __align__(16) u16 SM[3 * 4 * 64 * 32];   // 48KB  three bf16 stage buffers
  u16* Bs0 = SM;
  u16* Bs1 = SM + 8192;
  u16* Bs2 = SM + 16384;
  float* H1 = (float*)SM;                             // 32KB alias (used after attention phases)

  const int t = threadIdx.x;
  const int win = blockIdx.x;
  const int ihh = win / 24, iww = win % 24;
  const float SC = 0.17677669529663687f;              // 32^-0.5

  // ---------- gather + LN1 ----------
  // token n = (c = n>>1, half = n&1); cc -> (ys = half*4 + cc>>3, xs = cc&7)
  {
    const int e = t >> 6, n = t & 63;
    const int cch = n >> 1, hf = n & 1;
    const float* base = X + (e * 32 + cch) * 36864 + (ihh * 8) * 192 + iww * 8;
    float v[32];
    #pragma unroll
    for (int r = 0; r < 4; ++r){
      const float4* p4 = (const float4*)(base + (hf * 4 + r) * 192);
      float4 a = p4[0], b = p4[1];
      v[r*8+0]=a.x; v[r*8+1]=a.y; v[r*8+2]=a.z; v[r*8+3]=a.w;
      v[r*8+4]=b.x; v[r*8+5]=b.y; v[r*8+6]=b.z; v[r*8+7]=b.w;
    }
    float s = 0.f;
    #pragma unroll
    for (int i = 0; i < 32; ++i) s += v[i];
    const float mean = s * 0.03125f;
    float vs = 0.f;
    #pragma unroll
    for (int i = 0; i < 32; ++i){ const float d = v[i] - mean; vs = fmaf(d, d, vs); }
    const float rstd = rsqrtf(vs * 0.03125f + 1e-5f);
    float* dst = XW + (e << 11) + (n << 5);
    #pragma unroll
    for (int i = 0; i < 32; ++i) dst[i] = (v[i] - mean) * rstd * g1[i] + b1[i];
  }
  __syncthreads();

  float acc11[32], acc12[32];
  #pragma unroll
  for (int i = 0; i < 32; ++i){ acc11[i] = 0.f; acc12[i] = 0.f; }
  float sc[64];

  // ---------- SA (head dim 128 = 4 chunks of 32 over exposures; xw WITHOUT POS) ----------
  #pragma unroll
  for (int m = 0; m < 64; ++m) sc[m] = 0.f;
  for (int e = 0; e < 4; ++e){
    proj(Bs0, XW, e, Wsa, 0,   SC,  t);   // q chunk (scale folded)
    proj(Bs1, XW, e, Wsa, 128, 1.f, t);   // k chunk
    __syncthreads();
    score64<true>(Bs0, Bs1, sc, t);
    __syncthreads();
  }
  {  // swin relative-position bias: rpb[((dy+7)*15 + dx+7)*4 + h]
    const int h = t >> 6, n = t & 63;
    const int by = (n >> 3) + 7, bx = (n & 7) + 7;
    #pragma unroll
    for (int m = 0; m < 64; ++m){
      const int idx = (by - (m >> 3)) * 15 + (bx - (m & 7));
      sc[m] += rpb[idx * 4 + h];
    }
  }
  {
    const float rinv = softmax64(sc);
    for (int e = 0; e < 4; ++e){
      proj(Bs1, XW, e, Wsa, 256, 1.f, t); // v chunk
      __syncthreads();
      pv_store(Bs1, sc, rinv, Bs2, t);
      __syncthreads();
      mlp_acc(Bs2, (e << 5), W11, W12, acc11, acc12, t);  // feat rows h*128 + e*32 + k
      __syncthreads();
    }
  }

  // ---------- XW += POS (DETR sine enc, computed on the fly) ----------
  {
    const int n = t & 63;
    const int e = t >> 6;
    const float ye = (float)((n >> 3) + 1) * 0.7853980652f;  // 2*pi/(8+1e-6)
    const float xe = (float)((n & 7) + 1) * 0.7853980652f;
    float* row = XW + (e << 11) + (n << 5);
    #pragma unroll
    for (int cc = 0; cc < 32; ++cc){
      const int j = (cc & 15) >> 1;
      const float dimv = __expf(1.1512925465f * (float)j); // 10000^(j/8)
      const float arg = ((cc < 16) ? ye : xe) / dimv;
      row[cc] += (cc & 1) ? __cosf(arg) : __sinf(arg);
    }
  }
  __syncthreads();

  // ---------- EA1: attn(q0, k_e, v_e), feat rows 512 + h*128 + e*32 ----------
  proj(Bs0, XW, 0, Wea, 0, SC, t);        // q0, persists
  __syncthreads();
  for (int e = 0; e < 4; ++e){
    proj(Bs1, XW, e, Wea, 128, 1.f, t);   // k_e
    __syncthreads();
    score64<false>(Bs0, Bs1, sc, t);
    const float r2 = softmax64(sc);
    __syncthreads();
    proj(Bs1, XW, e, Wea, 256, 1.f, t);   // v_e
    __syncthreads();
    pv_store(Bs1, sc, r2, Bs2, t);
    __syncthreads();
    mlp_acc(Bs2, 512 + (e << 5), W11, W12, acc11, acc12, t);
    __syncthreads();
  }

  // ---------- EA2: attn(q_e, k0, v0), feat rows 1024 + h*128 + e*32 ----------
  proj(Bs0, XW, 0, Wea, 128, 1.f, t);     // k0, persists
  proj(Bs1, XW, 0, Wea, 256, 1.f, t);     // v0, persists
  __syncthreads();
  for (int e = 0; e < 4; ++e){
    proj(Bs2, XW, e, Wea, 0, SC, t);      // q_e
    __syncthreads();
    score64<false>(Bs2, Bs0, sc, t);
    const float r2 = softmax64(sc);
    __syncthreads();                      // q reads done before Bs2 reused as OC
    pv_store(Bs1, sc, r2, Bs2, t);
    __syncthreads();
    mlp_acc(Bs2, 1024 + (e << 5), W11, W12, acc11, acc12, t);
    __syncthreads();
  }

  // ---------- GEGLU gate -> H1 ----------
  {
    const int n = t >> 2, jb = t & 3;
    float* h1p = H1 + n * 128 + (jb << 5);
    #pragma unroll
    for (int i = 0; i < 32; ++i){
      const float vg = acc11[i] + B11[(jb << 5) + i];
      const float vl = acc12[i] + B12[(jb << 5) + i];
      h1p[i] = gelu_ex(vg) * vl;
    }
  }
  __syncthreads();

  // ---------- fc2 + faithful un-window + residual ----------
  // out[n][d]: e = d>>5, c = d&31; pixel h = (n>>3)*24 + ih, w = (n&7)*24 + iw
  {
    const int n = t >> 2, db = t & 3;
    float o[32];
    #pragma unroll
    for (int i = 0; i < 32; ++i) o[i] = B2v[(db << 5) + i];
    const float* h1p = H1 + n * 128;
    for (int j = 0; j < 128; ++j){
      const float hj = h1p[j];
      const float4* wr = (const float4*)(W2 + j * 128 + (db << 5));
      #pragma unroll
      for (int q = 0; q < 8; ++q){ float4 w4 = wr[q]; FMA4A(o, 4*q, hj, w4); }
    }
    const int hh = (n >> 3) * 24 + ihh;
    const int ww = (n & 7) * 24 + iww;
    const int pix = hh * 192 + ww;
    const float* xin = X + (db << 5) * 36864 + pix;
    float* op = OUT + (db << 5) * 36864 + pix;
    #pragma unroll
    for (int i = 0; i < 32; ++i) op[i * 36864] = o[i] + xin[i * 36864];
  }
}

// ---------- K2: LN2 + GEGLU MLP2 + residual, in-place on d_out ----------
__global__ __launch_bounds__(256, 2)
void k_mlp2(float* __restrict__ IO,
            const float* __restrict__ g2, const float* __restrict__ b2,
            const float* __restrict__ W11, const float* __restrict__ B11,
            const float* __restrict__ W12, const float* __restrict__ B12,
            const float* __restrict__ W2,  const float* __restrict__ B2v)
{
  __shared__ __align__(16) float T[128 * 64];  // x1 tile [f][pix]
  __shared__ __align__(16) float U[128 * 64];  // normalized, then hidden
  const int t = threadIdx.x;
  const int p0 = blockIdx.x << 6;

  #pragma unroll
  for (int i = 0; i < 32; ++i){
    const int idx = (i << 8) + t;
    const int f = idx >> 6, pix = idx & 63;
    T[(f << 6) + pix] = IO[f * 36864 + p0 + pix];
  }
  __syncthreads();

  const int pix = t & 63, quad = t >> 6;
  {
    float sum = 0.f, ss = 0.f;
    for (int f = 0; f < 128; ++f){ const float v = T[(f << 6) + pix]; sum += v; ss = fmaf(v, v, ss); }
    const float mean = sum * 0.0078125f;
    const float var = ss * 0.0078125f - mean * mean;
    const float rstd = rsqrtf(var + 1e-5f);
    const int f0 = quad << 5;
    for (int f = f0; f < f0 + 32; ++f)
      U[(f << 6) + pix] = (T[(f << 6) + pix] - mean) * rstd * g2[f] + b2[f];
  }
  __syncthreads();

  float a1[32], a2[32];
  #pragma unroll
  for (int i = 0; i < 32; ++i){ a1[i] = 0.f; a2[i] = 0.f; }
  const int joff = quad << 5;
  for (int f = 0; f < 128; ++f){
    const float xv = U[(f << 6) + pix];
    const float4* w1 = (const float4*)(W11 + f * 128 + joff);
    const float4* w2 = (const float4*)(W12 + f * 128 + joff);
    #pragma unroll
    for (int q = 0; q < 8; ++q){ float4 wa = w1[q]; FMA4A(a1, 4*q, xv, wa); }
    #pragma unroll
    for (int q = 0; q < 8; ++q){ float4 wb = w2[q]; FMA4A(a2, 4*q, xv, wb); }
  }
  float hid[32];
  #pragma unroll
  for (int i = 0; i < 32; ++i)
    hid[i] = gelu_ex(a1[i] + B11[joff + i]) * (a2[i] + B12[joff + i]);
  __syncthreads();
  #pragma unroll
  for (int i = 0; i < 32; ++i) U[((joff + i) << 6) + pix] = hid[i];
  __syncthreads();

  float o[32];
  #pragma unroll
  for (int i = 0; i < 32; ++i) o[i] = B2v[joff + i];
  for (int j = 0; j < 128; ++j){
    const float u = U[(j << 6) + pix];
    const float4* wr = (const float4*)(W2 + j * 128 + joff);
    #pragma unroll
    for (int q = 0; q < 8; ++q){ float4 w4 = wr[q]; FMA4A(o, 4*q, u, w4); }
  }
  #pragma unroll
  for (int i = 0; i < 32; ++i){
    const int f = joff + i;
    IO[f * 36864 + p0 + pix] = T[(f << 6) + pix] + o[i];
  }
}

extern "C" void kernel_launch(void* const* d_in, const int* in_sizes, int n_in,
                              void* d_out, int out_size, void* d_ws, size_t ws_size,
                              hipStream_t stream)
{
  (void)in_sizes; (void)n_in; (void)out_size; (void)d_ws; (void)ws_size;
  const float* X    = (const float*)d_in[0];
  const float* Wea  = (const float*)d_in[1];
  const float* Wsa  = (const float*)d_in[2];
  const float* g1   = (const float*)d_in[3];
  const float* b1   = (const float*)d_in[4];
  const float* g2   = (const float*)d_in[5];
  const float* b2   = (const float*)d_in[6];
  const float* rpb  = (const float*)d_in[7];
  const float* W11  = (const float*)d_in[8];
  const float* B11  = (const float*)d_in[9];
  const float* W12  = (const float*)d_in[10];
  const float* B12  = (const float*)d_in[11];
  const float* W2   = (const float*)d_in[12];
  const float* B2v  = (const float*)d_in[13];
  const float* m11  = (const float*)d_in[14];
  const float* mb11 = (const float*)d_in[15];
  const float* m12  = (const float*)d_in[16];
  const float* mb12 = (const float*)d_in[17];
  const float* m2w  = (const float*)d_in[18];
  const float* mb2  = (const float*)d_in[19];
  float* OUT = (float*)d_out;

  k_win<<<dim3(576), dim3(256), 0, stream>>>(X, Wea, Wsa, g1, b1, rpb,
                                             W11, B11, W12, B12, W2, B2v, OUT);
  k_mlp2<<<dim3(576), dim3(256), 0, stream>>>(OUT, g2, b2, m11, mb11, m12, mb12, m2w, mb2);
}